// Round 1
// baseline (2507.708 us; speedup 1.0000x reference)
//
#include <hip/hip_runtime.h>
#include <math.h>

#define NN 50000
#define NE 800000
#define HID 128
#define EPB 8
#define NPB 8

__device__ __forceinline__ float silu_(float x) {
    return x / (1.0f + __expf(-x));
}

__device__ __forceinline__ float wave_sum(float v) {
#pragma unroll
    for (int m = 32; m >= 1; m >>= 1) v += __shfl_xor(v, m, 64);
    return v;
}

// Accumulate 4 consecutive input rows (i4*4 .. i4*4+3) of weight matrix into NK
// per-edge accumulators. wp points at W[(row0)*HID + j]; sb is the LDS input tile.
template <int NK, int LD>
__device__ __forceinline__ void mlp4(const float* __restrict__ wp,
                                     const float (*sb)[LD], int i4,
                                     float* acc)
{
    const float w0 = wp[0];
    const float w1 = wp[HID];
    const float w2 = wp[2 * HID];
    const float w3 = wp[3 * HID];
#pragma unroll
    for (int k = 0; k < NK; ++k) {
        const float4 x = *(const float4*)&sb[k][i4 * 4];
        acc[k] = fmaf(x.x, w0, acc[k]);
        acc[k] = fmaf(x.y, w1, acc[k]);
        acc[k] = fmaf(x.z, w2, acc[k]);
        acc[k] = fmaf(x.w, w3, acc[k]);
    }
}

// Fold prompt (+bias) into per-layer constant pre-activation vectors.
// pre[0..127]=edge L1, [128..255]=node L1, [256..383]=ae L1, [384..511]=ap L1
__global__ __launch_bounds__(128) void pre_kernel(
    const float* __restrict__ prompt,
    const float* __restrict__ e_w1, const float* __restrict__ e_b1,
    const float* __restrict__ n_w1, const float* __restrict__ n_b1,
    const float* __restrict__ ae_w1, const float* __restrict__ ae_b1,
    const float* __restrict__ ap_w1, const float* __restrict__ ap_b1,
    float* __restrict__ pre)
{
    const int j = threadIdx.x;
    __shared__ float p[HID];
    p[j] = prompt[j];
    __syncthreads();
    float a0 = e_b1[j], a1 = n_b1[j], a2 = ae_b1[j], a3 = ap_b1[j];
    for (int k = 0; k < HID; ++k) {
        const float pk = p[k];
        a0 = fmaf(pk, e_w1[(273 + k) * HID + j], a0);
        a1 = fmaf(pk, n_w1[(256 + k) * HID + j], a1);
        a2 = fmaf(pk, ae_w1[(128 + k) * HID + j], a2);
        a3 = fmaf(pk, ap_w1[(128 + k) * HID + j], a3);
    }
    pre[j] = a0;
    pre[HID + j] = a1;
    pre[2 * HID + j] = a2;
    pre[3 * HID + j] = a3;
}

// Edge pass: edge MLP (2 layers) -> atomic agg into agg[row];
// acc-edge MLP -> scalar -> trans -> atomic agg_c[row].
__global__ __launch_bounds__(128) void edge_kernel(
    const float* __restrict__ h, const int* __restrict__ ei,
    const float* __restrict__ coord, const float* __restrict__ eattr,
    const float* __restrict__ e_w1, const float* __restrict__ e_w2,
    const float* __restrict__ e_b2,
    const float* __restrict__ ae_w1, const float* __restrict__ ae_w2,
    const float* __restrict__ pre,
    float* __restrict__ agg, float* __restrict__ agg_c)
{
    const int j = threadIdx.x;
    const int e0 = blockIdx.x * EPB;

    __shared__ __align__(16) float s_hr[EPB][HID];
    __shared__ __align__(16) float s_hc[EPB][HID];
    __shared__ __align__(16) float s_hid[EPB][HID];
    __shared__ __align__(16) float s_ef[EPB][HID];
    __shared__ __align__(16) float s_ea[EPB][16];
    __shared__ float s_rad[EPB];
    __shared__ float s_cd[EPB][3];
    __shared__ int s_row[EPB], s_col[EPB];
    __shared__ float s_part[EPB][2];

    if (j < EPB) {
        const int e = e0 + j;
        const int r = ei[e];
        const int c = ei[NE + e];
        s_row[j] = r;
        s_col[j] = c;
        const float dx = coord[r * 3 + 0] - coord[c * 3 + 0];
        const float dy = coord[r * 3 + 1] - coord[c * 3 + 1];
        const float dz = coord[r * 3 + 2] - coord[c * 3 + 2];
        s_cd[j][0] = dx; s_cd[j][1] = dy; s_cd[j][2] = dz;
        s_rad[j] = dx * dx + dy * dy + dz * dz;
    }
    __syncthreads();
#pragma unroll
    for (int k = 0; k < EPB; ++k) {
        s_hr[k][j] = h[(size_t)s_row[k] * HID + j];
        s_hc[k][j] = h[(size_t)s_col[k] * HID + j];
    }
    {
        const int k = j >> 4, i = j & 15;
        s_ea[k][i] = eattr[(size_t)(e0 + k) * 16 + i];
    }
    __syncthreads();

    // ---- edge MLP layer 1 (input rows: h_row 0..127, h_col 128..255,
    //      radial 256, edge_attr 257..272; prompt 273..400 folded into pre) ----
    float acc[EPB];
    {
        const float pe = pre[j];
        const float wr = e_w1[256 * HID + j];
#pragma unroll
        for (int k = 0; k < EPB; ++k) acc[k] = fmaf(s_rad[k], wr, pe);
    }
    for (int i4 = 0; i4 < 32; ++i4)
        mlp4<EPB, HID>(&e_w1[(i4 * 4) * HID + j], s_hr, i4, acc);
    for (int i4 = 0; i4 < 32; ++i4)
        mlp4<EPB, HID>(&e_w1[(128 + i4 * 4) * HID + j], s_hc, i4, acc);
    for (int i4 = 0; i4 < 4; ++i4)
        mlp4<EPB, 16>(&e_w1[(257 + i4 * 4) * HID + j], s_ea, i4, acc);
#pragma unroll
    for (int k = 0; k < EPB; ++k) s_hid[k][j] = silu_(acc[k]);
    __syncthreads();

    // ---- edge MLP layer 2 ----
    float acc2[EPB];
    {
        const float b = e_b2[j];
#pragma unroll
        for (int k = 0; k < EPB; ++k) acc2[k] = b;
    }
    for (int i4 = 0; i4 < 32; ++i4)
        mlp4<EPB, HID>(&e_w2[(i4 * 4) * HID + j], s_hid, i4, acc2);
#pragma unroll
    for (int k = 0; k < EPB; ++k) {
        const float ef = silu_(acc2[k]);
        s_ef[k][j] = ef;
        atomicAdd(&agg[(size_t)s_row[k] * HID + j], ef);
    }
    __syncthreads();

    // ---- acc-edge MLP: silu([ef, prompt] @ ae_w1 + b) @ ae_w2 -> scalar ----
    float acc3[EPB];
    {
        const float pa = pre[2 * HID + j];
#pragma unroll
        for (int k = 0; k < EPB; ++k) acc3[k] = pa;
    }
    for (int i4 = 0; i4 < 32; ++i4)
        mlp4<EPB, HID>(&ae_w1[(i4 * 4) * HID + j], s_ef, i4, acc3);
    {
        const float w2v = ae_w2[j];
        const int lane = j & 63, wv = j >> 6;
#pragma unroll
        for (int k = 0; k < EPB; ++k) {
            float v = silu_(acc3[k]) * w2v;
            v = wave_sum(v);
            if (lane == 0) s_part[k][wv] = v;
        }
    }
    __syncthreads();
    if (j < EPB * 3) {
        const int k = j / 3, d = j % 3;
        const float s = s_part[k][0] + s_part[k][1];
        const float nrm = fmaxf(sqrtf(s_rad[k]), 1e-12f);
        const float tr = s_cd[k][d] / nrm * s;
        atomicAdd(&agg_c[(size_t)s_row[k] * 3 + d], tr);
    }
}

// Node pass: node MLP (residual) -> h_out; ap MLP scalar -> acc = agg_c * s;
// coord copied through.
__global__ __launch_bounds__(128) void node_kernel(
    const float* __restrict__ h, const float* __restrict__ coord,
    const float* __restrict__ n_w1, const float* __restrict__ n_w2,
    const float* __restrict__ n_b2,
    const float* __restrict__ ap_w1, const float* __restrict__ ap_w2,
    const float* __restrict__ pre, const float* __restrict__ agg_c,
    float* __restrict__ out_h, float* __restrict__ out_coord,
    float* __restrict__ out_acc)
{
    const int j = threadIdx.x;
    const int n0 = blockIdx.x * NPB;

    __shared__ __align__(16) float s_h[NPB][HID];
    __shared__ __align__(16) float s_ag[NPB][HID];
    __shared__ __align__(16) float s_hid[NPB][HID];
    __shared__ __align__(16) float s_ho[NPB][HID];
    __shared__ float s_part[NPB][2];

#pragma unroll
    for (int k = 0; k < NPB; ++k) {
        s_h[k][j] = h[(size_t)(n0 + k) * HID + j];
        s_ag[k][j] = out_h[(size_t)(n0 + k) * HID + j];  // agg lives here
    }
    __syncthreads();

    // ---- node MLP layer 1 (h 0..127, agg 128..255; prompt folded) ----
    float acc[NPB];
    {
        const float pn = pre[HID + j];
#pragma unroll
        for (int k = 0; k < NPB; ++k) acc[k] = pn;
    }
    for (int i4 = 0; i4 < 32; ++i4)
        mlp4<NPB, HID>(&n_w1[(i4 * 4) * HID + j], s_h, i4, acc);
    for (int i4 = 0; i4 < 32; ++i4)
        mlp4<NPB, HID>(&n_w1[(128 + i4 * 4) * HID + j], s_ag, i4, acc);
#pragma unroll
    for (int k = 0; k < NPB; ++k) s_hid[k][j] = silu_(acc[k]);
    __syncthreads();

    // ---- node MLP layer 2 + residual ----
    float acc2[NPB];
    {
        const float b = n_b2[j];
#pragma unroll
        for (int k = 0; k < NPB; ++k) acc2[k] = b;
    }
    for (int i4 = 0; i4 < 32; ++i4)
        mlp4<NPB, HID>(&n_w2[(i4 * 4) * HID + j], s_hid, i4, acc2);
#pragma unroll
    for (int k = 0; k < NPB; ++k) {
        const float ho = s_h[k][j] + silu_(acc2[k]);
        s_ho[k][j] = ho;
        out_h[(size_t)(n0 + k) * HID + j] = ho;
    }
    __syncthreads();

    // ---- acc-point MLP: silu([h_out, prompt] @ ap_w1 + b) @ ap_w2 ----
    float acc3[NPB];
    {
        const float pp = pre[3 * HID + j];
#pragma unroll
        for (int k = 0; k < NPB; ++k) acc3[k] = pp;
    }
    for (int i4 = 0; i4 < 32; ++i4)
        mlp4<NPB, HID>(&ap_w1[(i4 * 4) * HID + j], s_ho, i4, acc3);
    {
        const float w2v = ap_w2[j];
        const int lane = j & 63, wv = j >> 6;
#pragma unroll
        for (int k = 0; k < NPB; ++k) {
            float v = silu_(acc3[k]) * w2v;
            v = wave_sum(v);
            if (lane == 0) s_part[k][wv] = v;
        }
    }
    __syncthreads();
    if (j < NPB * 3) {
        const int k = j / 3, d = j % 3;
        const int n = n0 + k;
        const float s = s_part[k][0] + s_part[k][1];
        out_acc[(size_t)n * 3 + d] = agg_c[(size_t)n * 3 + d] * s;
        out_coord[(size_t)n * 3 + d] = coord[(size_t)n * 3 + d];
    }
}

extern "C" void kernel_launch(void* const* d_in, const int* in_sizes, int n_in,
                              void* d_out, int out_size, void* d_ws, size_t ws_size,
                              hipStream_t stream)
{
    const float* h      = (const float*)d_in[0];
    const int*   ei     = (const int*)d_in[1];
    const float* coord  = (const float*)d_in[2];
    const float* eattr  = (const float*)d_in[3];
    const float* prompt = (const float*)d_in[4];
    const float* e_w1 = (const float*)d_in[5];
    const float* e_b1 = (const float*)d_in[6];
    const float* e_w2 = (const float*)d_in[7];
    const float* e_b2 = (const float*)d_in[8];
    const float* n_w1 = (const float*)d_in[9];
    const float* n_b1 = (const float*)d_in[10];
    const float* n_w2 = (const float*)d_in[11];
    const float* n_b2 = (const float*)d_in[12];
    const float* ae_w1 = (const float*)d_in[13];
    const float* ae_b1 = (const float*)d_in[14];
    const float* ae_w2 = (const float*)d_in[15];
    const float* ap_w1 = (const float*)d_in[16];
    const float* ap_b1 = (const float*)d_in[17];
    const float* ap_w2 = (const float*)d_in[18];

    float* out       = (float*)d_out;
    float* out_h     = out;                              // [NN,128] (agg during edge pass)
    float* out_coord = out + (size_t)NN * HID;           // [NN,3]
    float* out_acc   = out_coord + (size_t)NN * 3;       // [NN,3]

    float* agg   = out_h;                                // reuse h_out slot as agg
    float* agg_c = (float*)d_ws;                         // [NN,3]
    float* pre   = agg_c + (size_t)NN * 3;               // [512]

    hipMemsetAsync(agg, 0, (size_t)NN * HID * sizeof(float), stream);
    hipMemsetAsync(agg_c, 0, (size_t)NN * 3 * sizeof(float), stream);

    pre_kernel<<<1, 128, 0, stream>>>(prompt, e_w1, e_b1, n_w1, n_b1,
                                      ae_w1, ae_b1, ap_w1, ap_b1, pre);
    edge_kernel<<<NE / EPB, 128, 0, stream>>>(h, ei, coord, eattr,
                                              e_w1, e_w2, e_b2, ae_w1, ae_w2,
                                              pre, agg, agg_c);
    node_kernel<<<NN / NPB, 128, 0, stream>>>(h, coord, n_w1, n_w2, n_b2,
                                              ap_w1, ap_w2, pre, agg_c,
                                              out_h, out_coord, out_acc);
}

// Round 2
// 906.128 us; speedup vs baseline: 2.7675x; 2.7675x over previous
//
#include <hip/hip_runtime.h>
#include <math.h>

#define NN 50000
#define NE 800000
#define HID 128

typedef __attribute__((ext_vector_type(8))) short short8;
typedef __attribute__((ext_vector_type(4))) float f32x4;

#define MFMA(a, b, c) __builtin_amdgcn_mfma_f32_16x16x32_bf16(a, b, c, 0, 0, 0)

__device__ __forceinline__ float silu_(float x) {
    return x / (1.0f + __expf(-x));
}

// f32 -> bf16 bits, round-to-nearest-even
__device__ __forceinline__ short f2bf(float f) {
    union { float f; unsigned u; } v;
    v.f = f;
    unsigned r = v.u + 0x7fffu + ((v.u >> 16) & 1u);
    return (short)(r >> 16);
}

__device__ __forceinline__ float red16(float v) {
    v += __shfl_xor(v, 1, 16);
    v += __shfl_xor(v, 2, 16);
    v += __shfl_xor(v, 4, 16);
    v += __shfl_xor(v, 8, 16);
    return v;
}

// ---------------------------------------------------------------------------
// Fold prompt (+bias) into per-layer constant pre-activation vectors.
// pre[0..127]=edge L1, [128..255]=node L1, [256..383]=ae L1, [384..511]=ap L1
__global__ __launch_bounds__(128) void pre_kernel(
    const float* __restrict__ prompt,
    const float* __restrict__ e_w1, const float* __restrict__ e_b1,
    const float* __restrict__ n_w1, const float* __restrict__ n_b1,
    const float* __restrict__ ae_w1, const float* __restrict__ ae_b1,
    const float* __restrict__ ap_w1, const float* __restrict__ ap_b1,
    float* __restrict__ pre)
{
    const int j = threadIdx.x;
    __shared__ float p[HID];
    p[j] = prompt[j];
    __syncthreads();
    float a0 = e_b1[j], a1 = n_b1[j], a2 = ae_b1[j], a3 = ap_b1[j];
    for (int k = 0; k < HID; ++k) {
        const float pk = p[k];
        a0 = fmaf(pk, e_w1[(273 + k) * HID + j], a0);
        a1 = fmaf(pk, n_w1[(256 + k) * HID + j], a1);
        a2 = fmaf(pk, ae_w1[(128 + k) * HID + j], a2);
        a3 = fmaf(pk, ap_w1[(128 + k) * HID + j], a3);
    }
    pre[j] = a0;
    pre[HID + j] = a1;
    pre[2 * HID + j] = a2;
    pre[3 * HID + j] = a3;
}

// ---------------------------------------------------------------------------
// Swizzle all weight matrices into bf16 B-fragment layout:
// frag (kt,nt): element (lane l, i) = W[kt*32 + (l>>4)*8 + i][nt*16 + (l&15)]
// frag ids: e_w1 0..71 (9x8, K=288 with eattr shift+pad), e_w2 72..103,
//           ae_w1 104..135, n_w1 136..199 (8x8), n_w2 200..231, ap_w1 232..263
__global__ __launch_bounds__(64) void prep_weights(
    const float* __restrict__ e_w1, const float* __restrict__ e_w2,
    const float* __restrict__ ae_w1, const float* __restrict__ n_w1,
    const float* __restrict__ n_w2, const float* __restrict__ ap_w1,
    short* __restrict__ wsw)
{
    const int fid = blockIdx.x;
    const int l = threadIdx.x;
    int kt, nt;
    const float* W = nullptr;
    int kmax = 128;
    int e1 = 0;
    if (fid < 72) { kt = fid >> 3; nt = fid & 7; e1 = 1; }
    else if (fid < 104) { int f = fid - 72;  kt = f >> 3; nt = f & 7; W = e_w2; }
    else if (fid < 136) { int f = fid - 104; kt = f >> 3; nt = f & 7; W = ae_w1; }
    else if (fid < 200) { int f = fid - 136; kt = f >> 3; nt = f & 7; W = n_w1; kmax = 256; }
    else if (fid < 232) { int f = fid - 200; kt = f >> 3; nt = f & 7; W = n_w2; }
    else                { int f = fid - 232; kt = f >> 3; nt = f & 7; W = ap_w1; }

    short8 v;
#pragma unroll
    for (int i = 0; i < 8; ++i) {
        const int k = kt * 32 + ((l >> 4) * 8) + i;
        const int n = nt * 16 + (l & 15);
        float f = 0.0f;
        if (e1) {
            // X layout: k 0..255 = h_row|h_col (rows 0..255), k 256..271 =
            // eattr (rows 257..272; row 256 is radial, handled in epilogue),
            // k 272..287 = zero pad
            if (k < 256) f = e_w1[k * HID + n];
            else if (k < 272) f = e_w1[(k + 1) * HID + n];
        } else {
            if (k < kmax) f = W[k * HID + n];
        }
        v[i] = f2bf(f);
    }
    *(short8*)&wsw[(size_t)fid * 512 + l * 8] = v;
}

// ---------------------------------------------------------------------------
// Edge pass: 64 edges/block, 2 waves. MFMA edge MLP (K=288, K=128), atomic agg;
// AE MLP -> scalar -> trans -> atomic agg_c.
__global__ __launch_bounds__(128, 2) void edge_kernel(
    const float* __restrict__ h, const int* __restrict__ ei,
    const float* __restrict__ coord, const float* __restrict__ eattr,
    const short* __restrict__ Bw1, const short* __restrict__ Bw2,
    const short* __restrict__ Bae,
    const float* __restrict__ e_w1,  // radial row 256
    const float* __restrict__ e_b2,
    const float* __restrict__ ae_w2, const float* __restrict__ pre,
    float* __restrict__ agg, float* __restrict__ agg_c)
{
    const int t = threadIdx.x;
    const int wv = t >> 6, l = t & 63;
    const int e0 = blockIdx.x * 64;
    const int ntb = wv * 4;

    __shared__ __align__(16) short xf[4 * 9 * 64 * 8];  // A frags: [mt][kt][lane][8]
    __shared__ __align__(16) short hf[4 * 4 * 64 * 8];  // hidden frags
    __shared__ int s_row[64], s_col[64];
    __shared__ float s_rad[64];
    __shared__ float s_cd[64][3];
    __shared__ float s_part[64][2];

    if (t < 64) {
        const int e = e0 + t;
        const int r = ei[e];
        const int c = ei[NE + e];
        s_row[t] = r; s_col[t] = c;
        const float dx = coord[r * 3 + 0] - coord[c * 3 + 0];
        const float dy = coord[r * 3 + 1] - coord[c * 3 + 1];
        const float dz = coord[r * 3 + 2] - coord[c * 3 + 2];
        s_cd[t][0] = dx; s_cd[t][1] = dy; s_cd[t][2] = dz;
        s_rad[t] = dx * dx + dy * dy + dz * dz;
    }
    __syncthreads();

    // ---- build X tile (bf16 A-fragment layout) ----
    // h_row (k 0..127) + h_col (k 128..255): chunk c -> q8 = c>>6, m = c&63
#pragma unroll
    for (int it = 0; it < 16; ++it) {
        const int c = it * 128 + t;
        const int q8 = c >> 6, m = c & 63;
        const int src = (q8 < 16) ? s_row[m] : s_col[m];
        const float* p = h + (size_t)src * HID + (q8 & 15) * 8;
        const float4 lo = *(const float4*)p;
        const float4 hi = *(const float4*)(p + 4);
        short8 v;
        v[0] = f2bf(lo.x); v[1] = f2bf(lo.y); v[2] = f2bf(lo.z); v[3] = f2bf(lo.w);
        v[4] = f2bf(hi.x); v[5] = f2bf(hi.y); v[6] = f2bf(hi.z); v[7] = f2bf(hi.w);
        const int kt = q8 >> 2, q = q8 & 3, mt = m >> 4, mr = m & 15;
        *(short8*)&xf[(((mt * 9 + kt) * 64) + q * 16 + mr) * 8] = v;
    }
    // eattr (k 256..271) + pad (k 272..287): kt = 8
#pragma unroll
    for (int it = 0; it < 2; ++it) {
        const int c = it * 128 + t;
        const int qv = c >> 6, m = c & 63;
        short8 v = {0, 0, 0, 0, 0, 0, 0, 0};
        if (qv < 2) {
            const float* p = eattr + (size_t)(e0 + m) * 16 + qv * 8;
            const float4 lo = *(const float4*)p;
            const float4 hi = *(const float4*)(p + 4);
            v[0] = f2bf(lo.x); v[1] = f2bf(lo.y); v[2] = f2bf(lo.z); v[3] = f2bf(lo.w);
            v[4] = f2bf(hi.x); v[5] = f2bf(hi.y); v[6] = f2bf(hi.z); v[7] = f2bf(hi.w);
        }
        const int mt = m >> 4, mr = m & 15;
        *(short8*)&xf[(((mt * 9 + 8) * 64) + qv * 16 + mr) * 8] = v;
    }
    __syncthreads();

    // ---- edge MLP layer 1: K = 288 ----
    f32x4 acc[4][4];
#pragma unroll
    for (int mt = 0; mt < 4; ++mt)
#pragma unroll
        for (int tt = 0; tt < 4; ++tt)
            acc[mt][tt] = (f32x4){0.f, 0.f, 0.f, 0.f};
    for (int kt = 0; kt < 9; ++kt) {
        short8 a[4], b[4];
#pragma unroll
        for (int mt = 0; mt < 4; ++mt) a[mt] = *(const short8*)&xf[((mt * 9 + kt) * 64 + l) * 8];
#pragma unroll
        for (int tt = 0; tt < 4; ++tt) b[tt] = *(const short8*)&Bw1[(((kt * 8) + ntb + tt) * 64 + l) * 8];
#pragma unroll
        for (int mt = 0; mt < 4; ++mt)
#pragma unroll
            for (int tt = 0; tt < 4; ++tt)
                acc[mt][tt] = MFMA(a[mt], b[tt], acc[mt][tt]);
    }
    // epilogue: + pre (bias+prompt) + radial*w_r, silu, -> hidden frags
    {
        float pe[4], wr[4];
#pragma unroll
        for (int tt = 0; tt < 4; ++tt) {
            const int n = (ntb + tt) * 16 + (l & 15);
            pe[tt] = pre[n];
            wr[tt] = e_w1[256 * HID + n];
        }
#pragma unroll
        for (int mt = 0; mt < 4; ++mt)
#pragma unroll
            for (int tt = 0; tt < 4; ++tt) {
                const int n = (ntb + tt) * 16 + (l & 15);
                const int lane2b = ((n >> 3) & 3) * 16;
                const int kt2 = n >> 5;
#pragma unroll
                for (int r = 0; r < 4; ++r) {
                    const int m = mt * 16 + (l >> 4) * 4 + r;
                    float v = acc[mt][tt][r] + pe[tt] + s_rad[m] * wr[tt];
                    v = silu_(v);
                    hf[((mt * 4 + kt2) * 64 + lane2b + (m & 15)) * 8 + (n & 7)] = f2bf(v);
                }
            }
    }
    __syncthreads();

    // ---- edge MLP layer 2: K = 128 ----
    f32x4 acc2[4][4];
    {
        float b2[4];
#pragma unroll
        for (int tt = 0; tt < 4; ++tt) b2[tt] = e_b2[(ntb + tt) * 16 + (l & 15)];
#pragma unroll
        for (int mt = 0; mt < 4; ++mt)
#pragma unroll
            for (int tt = 0; tt < 4; ++tt)
                acc2[mt][tt] = (f32x4){b2[tt], b2[tt], b2[tt], b2[tt]};
    }
    for (int kt = 0; kt < 4; ++kt) {
        short8 a[4], b[4];
#pragma unroll
        for (int mt = 0; mt < 4; ++mt) a[mt] = *(const short8*)&hf[((mt * 4 + kt) * 64 + l) * 8];
#pragma unroll
        for (int tt = 0; tt < 4; ++tt) b[tt] = *(const short8*)&Bw2[(((kt * 8) + ntb + tt) * 64 + l) * 8];
#pragma unroll
        for (int mt = 0; mt < 4; ++mt)
#pragma unroll
            for (int tt = 0; tt < 4; ++tt)
                acc2[mt][tt] = MFMA(a[mt], b[tt], acc2[mt][tt]);
    }
    // epilogue: ef = silu -> atomic agg + ef frags (reuse xf region)
#pragma unroll
    for (int mt = 0; mt < 4; ++mt)
#pragma unroll
        for (int tt = 0; tt < 4; ++tt) {
            const int n = (ntb + tt) * 16 + (l & 15);
            const int lane2b = ((n >> 3) & 3) * 16;
            const int kt2 = n >> 5;
#pragma unroll
            for (int r = 0; r < 4; ++r) {
                const int m = mt * 16 + (l >> 4) * 4 + r;
                const float v = silu_(acc2[mt][tt][r]);
                atomicAdd(&agg[(size_t)s_row[m] * HID + n], v);
                xf[((mt * 9 + kt2) * 64 + lane2b + (m & 15)) * 8 + (n & 7)] = f2bf(v);
            }
        }
    __syncthreads();

    // ---- AE MLP: K = 128 on ef, then dot with ae_w2 ----
    f32x4 acc3[4][4];
    float w2v[4];
    {
#pragma unroll
        for (int tt = 0; tt < 4; ++tt) {
            const int n = (ntb + tt) * 16 + (l & 15);
            const float pa = pre[2 * HID + n];
            w2v[tt] = ae_w2[n];
#pragma unroll
            for (int mt = 0; mt < 4; ++mt) (void)0;
            acc3[0][tt] = (f32x4){pa, pa, pa, pa};
            acc3[1][tt] = acc3[0][tt];
            acc3[2][tt] = acc3[0][tt];
            acc3[3][tt] = acc3[0][tt];
        }
    }
    for (int kt = 0; kt < 4; ++kt) {
        short8 a[4], b[4];
#pragma unroll
        for (int mt = 0; mt < 4; ++mt) a[mt] = *(const short8*)&xf[((mt * 9 + kt) * 64 + l) * 8];
#pragma unroll
        for (int tt = 0; tt < 4; ++tt) b[tt] = *(const short8*)&Bae[(((kt * 8) + ntb + tt) * 64 + l) * 8];
#pragma unroll
        for (int mt = 0; mt < 4; ++mt)
#pragma unroll
            for (int tt = 0; tt < 4; ++tt)
                acc3[mt][tt] = MFMA(a[mt], b[tt], acc3[mt][tt]);
    }
    // reduce: s[m] = sum_n silu(aehid[m][n]) * ae_w2[n]
#pragma unroll
    for (int mt = 0; mt < 4; ++mt) {
        float p0 = 0.f, p1 = 0.f, p2 = 0.f, p3 = 0.f;
#pragma unroll
        for (int tt = 0; tt < 4; ++tt) {
            p0 += silu_(acc3[mt][tt][0]) * w2v[tt];
            p1 += silu_(acc3[mt][tt][1]) * w2v[tt];
            p2 += silu_(acc3[mt][tt][2]) * w2v[tt];
            p3 += silu_(acc3[mt][tt][3]) * w2v[tt];
        }
        p0 = red16(p0); p1 = red16(p1); p2 = red16(p2); p3 = red16(p3);
        if ((l & 15) == 0) {
            const int mb = mt * 16 + (l >> 4) * 4;
            s_part[mb + 0][wv] = p0;
            s_part[mb + 1][wv] = p1;
            s_part[mb + 2][wv] = p2;
            s_part[mb + 3][wv] = p3;
        }
    }
    __syncthreads();
    if (t < 64) {
        const float s = s_part[t][0] + s_part[t][1];
        const float nrm = fmaxf(sqrtf(s_rad[t]), 1e-12f);
        const float f = s / nrm;
        const int row = s_row[t];
#pragma unroll
        for (int d = 0; d < 3; ++d)
            atomicAdd(&agg_c[(size_t)row * 3 + d], s_cd[t][d] * f);
    }
}

// ---------------------------------------------------------------------------
// Node pass: 64 nodes/block, 2 waves. node MLP (K=256, K=128) + residual,
// AP MLP -> scalar, acc = agg_c * s, coord copy. No atomics.
__global__ __launch_bounds__(128, 2) void node_kernel(
    const float* __restrict__ h, const float* __restrict__ coord,
    const short* __restrict__ Bn1, const short* __restrict__ Bn2,
    const short* __restrict__ Bap,
    const float* __restrict__ n_b2, const float* __restrict__ ap_w2,
    const float* __restrict__ pre,
    const float* agg,            // aliases out_h (agg accumulated there)
    const float* __restrict__ agg_c,
    float* out_h, float* __restrict__ out_coord, float* __restrict__ out_acc)
{
    const int t = threadIdx.x;
    const int wv = t >> 6, l = t & 63;
    const int n0 = blockIdx.x * 64;
    const int ntb = wv * 4;

    __shared__ __align__(16) short xn[4 * 8 * 64 * 8];  // [mt][kt(8)][lane][8]
    __shared__ __align__(16) short hn[4 * 4 * 64 * 8];
    __shared__ float s_part[64][2];

    // ---- build X = [h | agg] (K=256) ----
#pragma unroll
    for (int it = 0; it < 16; ++it) {
        const int c = it * 128 + t;
        const int q8 = c >> 6, m = c & 63;
        int node = n0 + m; if (node >= NN) node = NN - 1;
        const float* p = (q8 < 16) ? (h + (size_t)node * HID + q8 * 8)
                                   : (agg + (size_t)node * HID + (q8 - 16) * 8);
        const float4 lo = *(const float4*)p;
        const float4 hi = *(const float4*)(p + 4);
        short8 v;
        v[0] = f2bf(lo.x); v[1] = f2bf(lo.y); v[2] = f2bf(lo.z); v[3] = f2bf(lo.w);
        v[4] = f2bf(hi.x); v[5] = f2bf(hi.y); v[6] = f2bf(hi.z); v[7] = f2bf(hi.w);
        const int kt = q8 >> 2, q = q8 & 3, mt = m >> 4, mr = m & 15;
        *(short8*)&xn[(((mt * 8 + kt) * 64) + q * 16 + mr) * 8] = v;
    }
    __syncthreads();

    // ---- node MLP layer 1: K = 256 ----
    f32x4 acc[4][4];
#pragma unroll
    for (int mt = 0; mt < 4; ++mt)
#pragma unroll
        for (int tt = 0; tt < 4; ++tt)
            acc[mt][tt] = (f32x4){0.f, 0.f, 0.f, 0.f};
    for (int kt = 0; kt < 8; ++kt) {
        short8 a[4], b[4];
#pragma unroll
        for (int mt = 0; mt < 4; ++mt) a[mt] = *(const short8*)&xn[((mt * 8 + kt) * 64 + l) * 8];
#pragma unroll
        for (int tt = 0; tt < 4; ++tt) b[tt] = *(const short8*)&Bn1[(((kt * 8) + ntb + tt) * 64 + l) * 8];
#pragma unroll
        for (int mt = 0; mt < 4; ++mt)
#pragma unroll
            for (int tt = 0; tt < 4; ++tt)
                acc[mt][tt] = MFMA(a[mt], b[tt], acc[mt][tt]);
    }
    {
#pragma unroll
        for (int mt = 0; mt < 4; ++mt)
#pragma unroll
            for (int tt = 0; tt < 4; ++tt) {
                const int n = (ntb + tt) * 16 + (l & 15);
                const float pn = pre[HID + n];
                const int lane2b = ((n >> 3) & 3) * 16;
                const int kt2 = n >> 5;
#pragma unroll
                for (int r = 0; r < 4; ++r) {
                    const int m = mt * 16 + (l >> 4) * 4 + r;
                    const float v = silu_(acc[mt][tt][r] + pn);
                    hn[((mt * 4 + kt2) * 64 + lane2b + (m & 15)) * 8 + (n & 7)] = f2bf(v);
                }
            }
    }
    __syncthreads();

    // ---- node MLP layer 2 + residual -> h_out ----
    f32x4 acc2[4][4];
    {
        float b2[4];
#pragma unroll
        for (int tt = 0; tt < 4; ++tt) b2[tt] = n_b2[(ntb + tt) * 16 + (l & 15)];
#pragma unroll
        for (int mt = 0; mt < 4; ++mt)
#pragma unroll
            for (int tt = 0; tt < 4; ++tt)
                acc2[mt][tt] = (f32x4){b2[tt], b2[tt], b2[tt], b2[tt]};
    }
    for (int kt = 0; kt < 4; ++kt) {
        short8 a[4], b[4];
#pragma unroll
        for (int mt = 0; mt < 4; ++mt) a[mt] = *(const short8*)&hn[((mt * 4 + kt) * 64 + l) * 8];
#pragma unroll
        for (int tt = 0; tt < 4; ++tt) b[tt] = *(const short8*)&Bn2[(((kt * 8) + ntb + tt) * 64 + l) * 8];
#pragma unroll
        for (int mt = 0; mt < 4; ++mt)
#pragma unroll
            for (int tt = 0; tt < 4; ++tt)
                acc2[mt][tt] = MFMA(a[mt], b[tt], acc2[mt][tt]);
    }
#pragma unroll
    for (int mt = 0; mt < 4; ++mt)
#pragma unroll
        for (int tt = 0; tt < 4; ++tt) {
            const int n = (ntb + tt) * 16 + (l & 15);
            const int lane2b = ((n >> 3) & 3) * 16;
            const int kt2 = n >> 5;
#pragma unroll
            for (int r = 0; r < 4; ++r) {
                const int m = mt * 16 + (l >> 4) * 4 + r;
                const int node = n0 + m;
                const int node_c = node < NN ? node : NN - 1;
                const float hv = h[(size_t)node_c * HID + n];
                const float ho = hv + silu_(acc2[mt][tt][r]);
                if (node < NN) out_h[(size_t)node * HID + n] = ho;
                xn[((mt * 8 + kt2) * 64 + lane2b + (m & 15)) * 8 + (n & 7)] = f2bf(ho);
            }
        }
    __syncthreads();

    // ---- AP MLP: K = 128 on h_out, dot with ap_w2 ----
    f32x4 acc3[4][4];
    float w2v[4];
#pragma unroll
    for (int tt = 0; tt < 4; ++tt) {
        const int n = (ntb + tt) * 16 + (l & 15);
        const float pa = pre[3 * HID + n];
        w2v[tt] = ap_w2[n];
        acc3[0][tt] = (f32x4){pa, pa, pa, pa};
        acc3[1][tt] = acc3[0][tt];
        acc3[2][tt] = acc3[0][tt];
        acc3[3][tt] = acc3[0][tt];
    }
    for (int kt = 0; kt < 4; ++kt) {
        short8 a[4], b[4];
#pragma unroll
        for (int mt = 0; mt < 4; ++mt) a[mt] = *(const short8*)&xn[((mt * 8 + kt) * 64 + l) * 8];
#pragma unroll
        for (int tt = 0; tt < 4; ++tt) b[tt] = *(const short8*)&Bap[(((kt * 8) + ntb + tt) * 64 + l) * 8];
#pragma unroll
        for (int mt = 0; mt < 4; ++mt)
#pragma unroll
            for (int tt = 0; tt < 4; ++tt)
                acc3[mt][tt] = MFMA(a[mt], b[tt], acc3[mt][tt]);
    }
#pragma unroll
    for (int mt = 0; mt < 4; ++mt) {
        float p0 = 0.f, p1 = 0.f, p2 = 0.f, p3 = 0.f;
#pragma unroll
        for (int tt = 0; tt < 4; ++tt) {
            p0 += silu_(acc3[mt][tt][0]) * w2v[tt];
            p1 += silu_(acc3[mt][tt][1]) * w2v[tt];
            p2 += silu_(acc3[mt][tt][2]) * w2v[tt];
            p3 += silu_(acc3[mt][tt][3]) * w2v[tt];
        }
        p0 = red16(p0); p1 = red16(p1); p2 = red16(p2); p3 = red16(p3);
        if ((l & 15) == 0) {
            const int mb = mt * 16 + (l >> 4) * 4;
            s_part[mb + 0][wv] = p0;
            s_part[mb + 1][wv] = p1;
            s_part[mb + 2][wv] = p2;
            s_part[mb + 3][wv] = p3;
        }
    }
    __syncthreads();
    if (t < 64) {
        const int node = n0 + t;
        if (node < NN) {
            const float s = s_part[t][0] + s_part[t][1];
#pragma unroll
            for (int d = 0; d < 3; ++d) {
                out_acc[(size_t)node * 3 + d] = agg_c[(size_t)node * 3 + d] * s;
                out_coord[(size_t)node * 3 + d] = coord[(size_t)node * 3 + d];
            }
        }
    }
}

// ---------------------------------------------------------------------------
extern "C" void kernel_launch(void* const* d_in, const int* in_sizes, int n_in,
                              void* d_out, int out_size, void* d_ws, size_t ws_size,
                              hipStream_t stream)
{
    const float* h      = (const float*)d_in[0];
    const int*   ei     = (const int*)d_in[1];
    const float* coord  = (const float*)d_in[2];
    const float* eattr  = (const float*)d_in[3];
    const float* prompt = (const float*)d_in[4];
    const float* e_w1 = (const float*)d_in[5];
    const float* e_b1 = (const float*)d_in[6];
    const float* e_w2 = (const float*)d_in[7];
    const float* e_b2 = (const float*)d_in[8];
    const float* n_w1 = (const float*)d_in[9];
    const float* n_b1 = (const float*)d_in[10];
    const float* n_w2 = (const float*)d_in[11];
    const float* n_b2 = (const float*)d_in[12];
    const float* ae_w1 = (const float*)d_in[13];
    const float* ae_b1 = (const float*)d_in[14];
    const float* ae_w2 = (const float*)d_in[15];
    const float* ap_w1 = (const float*)d_in[16];
    const float* ap_b1 = (const float*)d_in[17];
    const float* ap_w2 = (const float*)d_in[18];

    float* out       = (float*)d_out;
    float* out_h     = out;                          // [NN,128] (agg during edge pass)
    float* out_coord = out + (size_t)NN * HID;       // [NN,3]
    float* out_acc   = out_coord + (size_t)NN * 3;   // [NN,3]
    float* agg       = out_h;

    float* agg_c = (float*)d_ws;                     // [NN,3]
    float* pre   = agg_c + (size_t)NN * 3;           // [512]
    short* wsw   = (short*)(pre + 512);              // 264 frags x 512 shorts

    const short* Bw1 = wsw;            // e_w1: 72 frags
    const short* Bw2 = wsw + 36864;    // e_w2: 32
    const short* Bae = wsw + 53248;    // ae_w1: 32
    const short* Bn1 = wsw + 69632;    // n_w1: 64
    const short* Bn2 = wsw + 102400;   // n_w2: 32
    const short* Bap = wsw + 118784;   // ap_w1: 32

    hipMemsetAsync(agg, 0, (size_t)NN * HID * sizeof(float), stream);
    hipMemsetAsync(agg_c, 0, (size_t)NN * 3 * sizeof(float), stream);

    pre_kernel<<<1, 128, 0, stream>>>(prompt, e_w1, e_b1, n_w1, n_b1,
                                      ae_w1, ae_b1, ap_w1, ap_b1, pre);
    prep_weights<<<264, 64, 0, stream>>>(e_w1, e_w2, ae_w1, n_w1, n_w2, ap_w1, wsw);

    edge_kernel<<<NE / 64, 128, 0, stream>>>(h, ei, coord, eattr,
                                             Bw1, Bw2, Bae, e_w1, e_b2, ae_w2,
                                             pre, agg, agg_c);
    node_kernel<<<(NN + 63) / 64, 128, 0, stream>>>(h, coord, Bn1, Bn2, Bap,
                                                    n_b2, ap_w2, pre,
                                                    agg, agg_c,
                                                    out_h, out_coord, out_acc);
}